// Round 6
// baseline (8897.652 us; speedup 1.0000x reference)
//
#include <hip/hip_runtime.h>
#include <hip/hip_bf16.h>
#include <stdint.h>

// CTRNN: B=64, T=1000, N_IN=128, N_REC=1024, N_OUT=64
// Persistent design, round 8 (barrier-free waves, full-K per wave):
//   grid = 64 WGs x 256 threads. WG = member m (owns 16 neurons, weff slab
//   32KB in LDS). Wave w = batch-plane w (batches 16w..16w+15). Each wave
//   computes its 16x16 output tile over the FULL K=1024 (32 rec-MFMAs +
//   4 x-MFMAs): no cross-wave reduction, NO __syncthreads in the main loop.
//   The 4 batch-planes are fully independent producer/consumer systems.
//   Evidence: R5 halved broadcast volume -> slower (3543 vs 3175us) =>
//   NOT bandwidth-bound; R2/R4/R5 cluster at 3.2-3.5us/step across very
//   different protocols => per-step serial chain bound. R4's chain was
//   poll-round quantization amplified by 2 intra-WG barriers/step (slowest
//   of 4 waves gates the WG twice, skew feeds back into more poll rounds)
//   + red[] LDS reduction. This round removes all three; protocol, MFMA
//   count, and traffic volumes are unchanged vs R4.
//   Exchange protocol (identical to passing R4 kernel): tag in bit31 of
//   each packed 32b h word (h=retanh>=0, sign free). Producer tags with
//   ((t+1)>>1)&1 and just stores (one 8B atomic per lane). Consumer:
//   per-chunk retry (32-bit pending mask, 32 chunks/lane) + s_sleep
//   backoff. Period-4 slot/phase disambiguation; a validated register
//   snapshot is final (h(t+2) cannot be written before this wave posts
//   h(t+1)); hbuf poisoned 0xFF so t=0/1 cannot false-accept.
//   State: lane owns 4 neurons x 1 batch as f32x4, matching the MFMA D
//   fragment (col=lane&15=batch, row=(lane>>4)*4+reg) -> epilogue is
//   4 fma + 4 tanh + 1 tagged 8B store, register-only.

#define B_    64
#define T_    1000
#define NIN   128
#define NREC  1024
#define NOUT  64
#define MEMBERS 64
#define NSL   16   // neurons per member

#define DT    0.1f

typedef short  bf16x8 __attribute__((ext_vector_type(8)));
typedef float  f32x4  __attribute__((ext_vector_type(4)));

#define SCOPE __HIP_MEMORY_SCOPE_AGENT

// ws layout
#define XB_OFF     0
#define XB_BYTES   (B_ * T_ * NIN * 2)                      // 16,384,000 (8B aligned)
#define HBUF_OFF   (XB_OFF + XB_BYTES)
#define HBUF_BYTES (2 * B_ * NREC * 2)                      // 262,144

#define TAGMASK 0x8000000080000000ull

union U16B { unsigned long long q[2]; bf16x8 s; };

__device__ __forceinline__ unsigned short f2bf(float f) {
    unsigned u = __float_as_uint(f);
    unsigned r = u + 0x7fffu + ((u >> 16) & 1u);
    return (unsigned short)(r >> 16);
}
__device__ __forceinline__ unsigned pack2(float lo, float hi) {
    return (unsigned)f2bf(lo) | ((unsigned)f2bf(hi) << 16);
}

__global__ void cast_x_kernel(const float* __restrict__ x, unsigned short* __restrict__ xb, int n4) {
    int i = blockIdx.x * blockDim.x + threadIdx.x;
    int stride = gridDim.x * blockDim.x;
    for (; i < n4; i += stride) {
        float4 v = ((const float4*)x)[i];
        unsigned lo = pack2(v.x, v.y);
        unsigned hi = pack2(v.z, v.w);
        ((uint2*)xb)[i] = make_uint2(lo, hi);
    }
}

__global__ __launch_bounds__(256, 1)
void rnn_main(const float* __restrict__ Wahx, const float* __restrict__ Wahh,
              const float* __restrict__ Wyh,  const float* __restrict__ bah,
              const float* __restrict__ by,   const float* __restrict__ ah0,
              const float* __restrict__ mask,
              const unsigned short* __restrict__ xb,
              unsigned short* __restrict__ hbuf,
              float* __restrict__ y)
{
    __shared__ unsigned short weff[NSL * NREC];   // 32 KB, swizzled rows
    __shared__ unsigned short wahxs[NSL * NIN];   // 4 KB, swizzled rows
    __shared__ unsigned short wyhs[NREC];         // 2 KB, single row o=m

    const int tid  = threadIdx.x;
    const int w    = tid >> 6;        // wave = batch-plane 0..3
    const int lane = tid & 63;
    const int m    = blockIdx.x;      // member 0..63

    // ---- init: build LDS slabs ----
    for (int cc = 0; cc < 8; ++cc) {
        int cid = cc * 256 + tid;           // 2048 chunks of 8
        int rl = cid >> 7;                  // local row 0..15
        int k  = (cid & 127) * 8;
        const float* wr = Wahh + (m * NSL + rl) * NREC + k;
        const float* mr = mask + (m * NSL + rl) * NREC + k;
        float4 a0 = *(const float4*)wr;     float4 a1 = *(const float4*)(wr + 4);
        float4 m0 = *(const float4*)mr;     float4 m1 = *(const float4*)(mr + 4);
        uint4 pk;
        pk.x = pack2(fabsf(a0.x) * m0.x, fabsf(a0.y) * m0.y);
        pk.y = pack2(fabsf(a0.z) * m0.z, fabsf(a0.w) * m0.w);
        pk.z = pack2(fabsf(a1.x) * m1.x, fabsf(a1.y) * m1.y);
        pk.w = pack2(fabsf(a1.z) * m1.z, fabsf(a1.w) * m1.w);
        int byte = (rl * 2048 + k * 2) ^ ((rl & 7) << 4);
        *(uint4*)((char*)weff + byte) = pk;
    }
    {
        int rl = tid >> 4;
        int k  = (tid & 15) * 8;
        const float* wr = Wahx + (m * NSL + rl) * NIN + k;
        float4 a0 = *(const float4*)wr;  float4 a1 = *(const float4*)(wr + 4);
        uint4 pk;
        pk.x = pack2(a0.x, a0.y); pk.y = pack2(a0.z, a0.w);
        pk.z = pack2(a1.x, a1.y); pk.w = pack2(a1.z, a1.w);
        int byte = (rl * 256 + k * 2) ^ ((rl & 7) << 4);
        *(uint4*)((char*)wahxs + byte) = pk;
    }
    if (tid < 128) {
        int k = tid * 8;
        const float* wr = Wyh + m * NREC + k;
        float4 a0 = *(const float4*)wr;  float4 a1 = *(const float4*)(wr + 4);
        uint4 pk;
        pk.x = pack2(a0.x, a0.y); pk.y = pack2(a0.z, a0.w);
        pk.z = pack2(a1.x, a1.y); pk.w = pack2(a1.z, a1.w);
        *(uint4*)((char*)wyhs + k * 2) = pk;
    }

    // geometry: lane -> (batch col, k-offset, 4 neuron rows)
    const int bcol = lane & 15;               // batch col / A row
    const int khi  = (lane >> 4) * 8;         // k offset within 32-chunk
    const int bg   = w * 16 + bcol;           // global batch
    const int nr0  = m * NSL + (lane >> 4) * 4;  // first of 4 owned neurons

    // register state: f32x4 matching D fragment (row = (lane>>4)*4 + reg)
    f32x4 ahv, bahv;
    #pragma unroll
    for (int r = 0; r < 4; ++r) { ahv[r] = ah0[nr0 + r]; bahv[r] = bah[nr0 + r]; }
    const float byv = by[m];

    unsigned long long* const hq_base = (unsigned long long*)hbuf;

    // h(0) = retanh(ah0) -> slot 0, tag 0 (natural sign bits); one 8B store
    {
        float h[4];
        #pragma unroll
        for (int r = 0; r < 4; ++r) { float th = tanhf(ahv[r]); h[r] = th > 0.f ? th : 0.f; }
        unsigned lo = (unsigned)f2bf(h[0]) | ((unsigned)f2bf(h[1]) << 16);
        unsigned hi = (unsigned)f2bf(h[2]) | ((unsigned)f2bf(h[3]) << 16);
        unsigned long long wq = (unsigned long long)lo | ((unsigned long long)hi << 32);
        __hip_atomic_store(hq_base + (((size_t)bg) << 8) + (nr0 >> 2), wq,
                           __ATOMIC_RELAXED, SCOPE);
    }
    __syncthreads();   // LDS slabs ready (the only barrier in the kernel)

    for (int t = 0; t <= T_; ++t) {
        // ---- prefetch x fragments (independent of h(t)) ----
        bf16x8 xf[4];
        if (t < T_) {
            const unsigned short* xp = xb + ((size_t)bg * T_ + t) * NIN;
            #pragma unroll
            for (int cx = 0; cx < 4; ++cx)
                xf[cx] = *(const bf16x8*)(xp + cx * 32 + khi);
        }

        // ---- poll-load h(t): 32 chunks/lane, per-chunk retry ----
        const int slot = t & 1;
        const unsigned long long want = ((t >> 1) & 1) ? TAGMASK : 0ull;
        const unsigned long long* bq =
            hq_base + (((size_t)(slot * B_ + bg)) << 8) + (khi >> 2);

        U16B u[32];
        unsigned pend = 0xFFFFFFFFu;
        for (;;) {
            #pragma unroll
            for (int c = 0; c < 32; ++c) if (pend & (1u << c)) {
                u[c].q[0] = __hip_atomic_load(bq + c * 8,     __ATOMIC_RELAXED, SCOPE);
                u[c].q[1] = __hip_atomic_load(bq + c * 8 + 1, __ATOMIC_RELAXED, SCOPE);
            }
            unsigned np = 0u;
            #pragma unroll
            for (int c = 0; c < 32; ++c) if (pend & (1u << c)) {
                if ((((u[c].q[0] ^ want) | (u[c].q[1] ^ want)) & TAGMASK) != 0ull)
                    np |= (1u << c);
            }
            pend = np;
            if (!__any(pend != 0u)) break;
            __builtin_amdgcn_s_sleep(1);   // backoff: don't hammer the LLC
        }
        bf16x8 bfrag[32];
        #pragma unroll
        for (int c = 0; c < 32; ++c) {
            u[c].q[0] &= ~TAGMASK;      // clear tags (real sign bits are 0)
            u[c].q[1] &= ~TAGMASK;
            bfrag[c] = u[c].s;
        }

        if (t < T_) {
            // ---- full-K recurrent GEMM in-wave: 4 chains, 36 MFMAs ----
            f32x4 z = {0.f, 0.f, 0.f, 0.f};
            f32x4 ch[4] = {z, z, z, z};
            #pragma unroll
            for (int cx = 0; cx < 4; ++cx) {
                int i = cx * 32 + khi;
                int byx = (bcol * 256 + i * 2) ^ ((bcol & 7) << 4);
                bf16x8 axf = *(const bf16x8*)((const char*)wahxs + byx);
                ch[cx] = __builtin_amdgcn_mfma_f32_16x16x32_bf16(axf, xf[cx], ch[cx], 0, 0, 0);
            }
            #pragma unroll
            for (int c = 0; c < 32; ++c) {
                int k = c * 32 + khi;
                int byw = (bcol * 2048 + k * 2) ^ ((bcol & 7) << 4);
                bf16x8 af = *(const bf16x8*)((const char*)weff + byw);
                ch[c & 3] = __builtin_amdgcn_mfma_f32_16x16x32_bf16(af, bfrag[c], ch[c & 3], 0, 0, 0);
            }
            f32x4 acc = (ch[0] + ch[1]) + (ch[2] + ch[3]);

            // ---- register epilogue: 4 neurons/lane, one tagged 8B store ----
            const unsigned tagw = ((unsigned)(((t + 1) >> 1) & 1)) << 31;
            float h[4];
            #pragma unroll
            for (int r = 0; r < 4; ++r) {
                ahv[r] = 0.9f * ahv[r] + DT * (acc[r] + bahv[r]);
                float th = tanhf(ahv[r]);
                h[r] = th > 0.f ? th : 0.f;
            }
            unsigned lo = (unsigned)f2bf(h[0]) | ((unsigned)f2bf(h[1]) << 16) | tagw;
            unsigned hi = (unsigned)f2bf(h[2]) | ((unsigned)f2bf(h[3]) << 16) | tagw;
            unsigned long long wq = (unsigned long long)lo | ((unsigned long long)hi << 32);
            __hip_atomic_store(hq_base + (((size_t)((slot ^ 1) * B_ + bg)) << 8) + (nr0 >> 2),
                               wq, __ATOMIC_RELAXED, SCOPE);
            // no ack, no flag: each word self-announces via its tag
        }

        // ---- y for output step t-1 (after the h store: off the inter-WG chain) ----
        if (t >= 1) {
            f32x4 z = {0.f, 0.f, 0.f, 0.f};
            f32x4 ych[4] = {z, z, z, z};
            #pragma unroll
            for (int c = 0; c < 32; ++c) {
                // broadcast read: A rows all = wyh[m] -> every D row = y
                bf16x8 wyf = *(const bf16x8*)((const char*)wyhs + (c * 32 + khi) * 2);
                ych[c & 3] = __builtin_amdgcn_mfma_f32_16x16x32_bf16(wyf, bfrag[c], ych[c & 3], 0, 0, 0);
            }
            f32x4 accy = (ych[0] + ych[1]) + (ych[2] + ych[3]);
            if (lane < 16) {
                float yv = accy[0] + byv;   // D row 0: reg 0 of lanes 0..15
                __builtin_nontemporal_store(yv,
                    &y[((size_t)(w * 16 + lane) * T_ + (t - 1)) * NOUT + m]);
            }
        }
    }
}

extern "C" void kernel_launch(void* const* d_in, const int* in_sizes, int n_in,
                              void* d_out, int out_size, void* d_ws, size_t ws_size,
                              hipStream_t stream) {
    const float* x    = (const float*)d_in[0];
    const float* Wahx = (const float*)d_in[1];
    const float* Wahh = (const float*)d_in[2];
    const float* Wyh  = (const float*)d_in[3];
    const float* bah  = (const float*)d_in[4];
    const float* by   = (const float*)d_in[5];
    const float* ah0  = (const float*)d_in[6];
    const float* mask = (const float*)d_in[7];
    float* y = (float*)d_out;
    char* ws = (char*)d_ws;
    unsigned short* xb   = (unsigned short*)(ws + XB_OFF);
    unsigned short* hbuf = (unsigned short*)(ws + HBUF_OFF);

    (void)in_sizes; (void)n_in; (void)out_size; (void)ws_size;

    // poison hbuf: all tag bits = 1, so phase-0 consumers (t=0,1) cannot
    // false-accept before the first writes land.
    hipMemsetAsync(hbuf, 0xFF, HBUF_BYTES, stream);
    cast_x_kernel<<<dim3(2048), dim3(256), 0, stream>>>(x, xb, (B_ * T_ * NIN) / 4);
    rnn_main<<<dim3(MEMBERS), dim3(256), 0, stream>>>(
        Wahx, Wahh, Wyh, bah, by, ah0, mask, xb, hbuf, y);
}

// Round 7
// 4045.475 us; speedup vs baseline: 2.1994x; 2.1994x over previous
//
#include <hip/hip_runtime.h>
#include <hip/hip_bf16.h>
#include <stdint.h>

// CTRNN: B=64, T=1000, N_IN=128, N_REC=1024, N_OUT=64
// Persistent-group design, round 9 (R4 base + eager chunks + single barrier):
//   grid = 256 WGs x 256 threads. group g = bid&3 (4 groups x 16 batches),
//   member m = bid>>2 (64 members, each owns 16 neurons and output o=m).
//   REVERTED from round-8's full-K waves (8898us: fan-in 64, 830MB FETCH,
//   64 CUs) to the verified R4 geometry (3175us: fan-in 16/wave, 8KB poll
//   set, 256 WGs).
//   Three chain cuts vs R4, protocol untouched:
//   1) EAGER CHUNKS: fire each chunk's rec- and y-MFMA the moment the chunk
//      becomes wave-ready (all 64 lanes' tags match) instead of waiting for
//      all 8 — overlaps h-load drain + GEMM with the poll tail.
//   2) y folded into the same compute phase (same bfrag) and same red[] /
//      barrier window -> ONE __syncthreads per step instead of two.
//   3) red[] double-buffered by t-parity. Safety: a wave rewrites red[p]
//      only at t+2, after its poll of h(t+2) succeeded, which transitively
//      requires every member's t+1 barrier, which orders all t-step red
//      reads (LDS is per-WG, so this is intra-WG only).
//   Exchange protocol (bit-identical to R4, twice verified): tag in bit31
//   of each packed 32b h word (h=retanh>=0, sign free). Producer tags with
//   ((t+1)>>1)&1 and just stores. Consumer: per-chunk retry with per-lane
//   pending mask + s_sleep backoff. Period-4 slot/phase disambiguation;
//   a validated snapshot is final (h(t+2) cannot be written before this
//   consumer posts h(t+1)); hbuf pre-poisoned 0xFF protects t=0/1.

#define B_    64
#define T_    1000
#define NIN   128
#define NREC  1024
#define NOUT  64
#define GROUPS  4
#define MEMBERS 64
#define BPG   16   // batches per group
#define NSL   16   // n-slice per member

#define DT    0.1f

typedef short  bf16x8 __attribute__((ext_vector_type(8)));
typedef float  f32x4  __attribute__((ext_vector_type(4)));

#define SCOPE __HIP_MEMORY_SCOPE_AGENT

// ws layout
#define XB_OFF     0
#define XB_BYTES   (B_ * T_ * NIN * 2)                      // 16,384,000 (16B aligned)
#define HBUF_OFF   (XB_OFF + XB_BYTES)
#define HBUF_BYTES (GROUPS * 2 * BPG * NREC * 2)            // 262,144

#define TAGMASK 0x8000000080000000ull

union U16B { unsigned long long q[2]; bf16x8 s; };

__device__ __forceinline__ unsigned short f2bf(float f) {
    unsigned u = __float_as_uint(f);
    unsigned r = u + 0x7fffu + ((u >> 16) & 1u);
    return (unsigned short)(r >> 16);
}
__device__ __forceinline__ unsigned pack2(float lo, float hi) {
    return (unsigned)f2bf(lo) | ((unsigned)f2bf(hi) << 16);
}

__global__ void cast_x_kernel(const float* __restrict__ x, unsigned short* __restrict__ xb, int n4) {
    int i = blockIdx.x * blockDim.x + threadIdx.x;
    int stride = gridDim.x * blockDim.x;
    for (; i < n4; i += stride) {
        float4 v = ((const float4*)x)[i];
        unsigned lo = pack2(v.x, v.y);
        unsigned hi = pack2(v.z, v.w);
        ((uint2*)xb)[i] = make_uint2(lo, hi);
    }
}

__global__ __launch_bounds__(256, 1)
void rnn_main(const float* __restrict__ Wahx, const float* __restrict__ Wahh,
              const float* __restrict__ Wyh,  const float* __restrict__ bah,
              const float* __restrict__ by,   const float* __restrict__ ah0,
              const float* __restrict__ mask,
              const unsigned short* __restrict__ xb,
              unsigned short* __restrict__ hbuf,
              float* __restrict__ y)
{
    __shared__ unsigned short weff[NSL * NREC];   // 32 KB, swizzled rows
    __shared__ unsigned short wahxs[NSL * NIN];   // 4 KB, swizzled rows
    __shared__ unsigned short wyhs[NREC];         // 2 KB, single row o=m
    __shared__ float red[2][4][2][64][4];         // 16 KB: [par][wave][rec/y][lane][reg]

    const int tid  = threadIdx.x;
    const int w    = tid >> 6;        // wave 0..3 (K-range w*256..)
    const int lane = tid & 63;
    const int bid  = blockIdx.x;
    const int g    = bid & 3;         // group
    const int m    = bid >> 2;        // member 0..63

    // ---- init: build LDS slabs ----
    for (int cc = 0; cc < 8; ++cc) {
        int cid = cc * 256 + tid;           // 2048 chunks of 8
        int rl = cid >> 7;                  // local row 0..15
        int k  = (cid & 127) * 8;
        const float* wr = Wahh + (m * NSL + rl) * NREC + k;
        const float* mr = mask + (m * NSL + rl) * NREC + k;
        float4 a0 = *(const float4*)wr;     float4 a1 = *(const float4*)(wr + 4);
        float4 m0 = *(const float4*)mr;     float4 m1 = *(const float4*)(mr + 4);
        uint4 pk;
        pk.x = pack2(fabsf(a0.x) * m0.x, fabsf(a0.y) * m0.y);
        pk.y = pack2(fabsf(a0.z) * m0.z, fabsf(a0.w) * m0.w);
        pk.z = pack2(fabsf(a1.x) * m1.x, fabsf(a1.y) * m1.y);
        pk.w = pack2(fabsf(a1.z) * m1.z, fabsf(a1.w) * m1.w);
        int byte = (rl * 2048 + k * 2) ^ ((rl & 7) << 4);
        *(uint4*)((char*)weff + byte) = pk;
    }
    {
        int rl = tid >> 4;
        int k  = (tid & 15) * 8;
        const float* wr = Wahx + (m * NSL + rl) * NIN + k;
        float4 a0 = *(const float4*)wr;  float4 a1 = *(const float4*)(wr + 4);
        uint4 pk;
        pk.x = pack2(a0.x, a0.y); pk.y = pack2(a0.z, a0.w);
        pk.z = pack2(a1.x, a1.y); pk.w = pack2(a1.z, a1.w);
        int byte = (rl * 256 + k * 2) ^ ((rl & 7) << 4);
        *(uint4*)((char*)wahxs + byte) = pk;
    }
    if (tid < 128) {
        int k = tid * 8;
        const float* wr = Wyh + m * NREC + k;
        float4 a0 = *(const float4*)wr;  float4 a1 = *(const float4*)(wr + 4);
        uint4 pk;
        pk.x = pack2(a0.x, a0.y); pk.y = pack2(a0.z, a0.w);
        pk.z = pack2(a1.x, a1.y); pk.w = pack2(a1.z, a1.w);
        *(uint4*)((char*)wyhs + k * 2) = pk;
    }

    // per-thread state: (b_loc, nl)
    const int b_loc = tid >> 4;
    const int nl    = tid & 15;
    const int n_g   = m * NSL + nl;
    float ahv  = ah0[n_g];
    float bahv = bah[n_g];
    float byv  = by[m];

    // h(0) = retanh(ah0) -> hbuf slot 0, tag 0 (natural sign bits)
    {
        float th = tanhf(ahv);
        float h0 = th > 0.f ? th : 0.f;
        unsigned hb = f2bf(h0);
        unsigned nb = __shfl_down(hb, 1);
        if ((nl & 1) == 0) {
            unsigned w32 = hb | (nb << 16);
            int eidx = ((g * 2 + 0) * BPG + b_loc) * NREC + n_g;
            __hip_atomic_store((unsigned*)hbuf + (eidx >> 1), w32, __ATOMIC_RELAXED, SCOPE);
        }
    }
    __syncthreads();   // LDS slabs ready before use

    const int bcol = lane & 15;          // batch col for MFMA, also A row
    const int khi  = (lane >> 4) * 8;    // per-lane k offset within 32-chunk

    for (int t = 0; t <= T_; ++t) {
        // ---- prefetch x fragment (independent of h(t)) ----
        bf16x8 xf, axf;
        if (t < T_) {
            int i = w * 32 + khi;
            xf = *(const bf16x8*)(xb + ((size_t)(g * BPG + bcol) * T_ + t) * NIN + i);
            int byte = (bcol * 256 + i * 2) ^ ((bcol & 7) << 4);
            axf = *(const bf16x8*)((const char*)wahxs + byte);
        }

        const int slot = t & 1;
        const unsigned long long want = ((t >> 1) & 1) ? TAGMASK : 0ull;
        const unsigned long long* hq =
            (const unsigned long long*)(hbuf + ((g * 2 + slot) * BPG + bcol) * NREC);

        f32x4 z = {0.f, 0.f, 0.f, 0.f};
        f32x4 ch0 = z, ch1 = z, yc0 = z, yc1 = z;
        if (t < T_)
            ch0 = __builtin_amdgcn_mfma_f32_16x16x32_bf16(axf, xf, ch0, 0, 0, 0);

        // ---- eager poll: per-chunk retry; fire MFMAs as chunks go wave-ready ----
        U16B u[8];
        bf16x8 bfrag[8];
        unsigned pend  = 0xFFu;          // per-lane: chunks whose tags failed
        unsigned fired = 0u;             // wave-uniform: chunks consumed
        while (fired != 0xFFu) {
            #pragma unroll
            for (int c = 0; c < 8; ++c) if (pend & (1u << c)) {
                int k = w * 256 + c * 32 + khi;
                u[c].q[0] = __hip_atomic_load(hq + (k >> 2),     __ATOMIC_RELAXED, SCOPE);
                u[c].q[1] = __hip_atomic_load(hq + (k >> 2) + 1, __ATOMIC_RELAXED, SCOPE);
            }
            #pragma unroll
            for (int c = 0; c < 8; ++c) if (pend & (1u << c)) {
                if ((((u[c].q[0] ^ want) | (u[c].q[1] ^ want)) & TAGMASK) == 0ull)
                    pend &= ~(1u << c);
            }
            #pragma unroll
            for (int c = 0; c < 8; ++c) if (!(fired & (1u << c))) {
                if (!__any(pend & (1u << c))) {       // all 64 lanes validated chunk c
                    u[c].q[0] &= ~TAGMASK;            // clear tags (real sign bits are 0)
                    u[c].q[1] &= ~TAGMASK;
                    bfrag[c] = u[c].s;
                    int k = w * 256 + c * 32 + khi;
                    if (t < T_) {
                        int byw = (bcol * 2048 + k * 2) ^ ((bcol & 7) << 4);
                        bf16x8 af = *(const bf16x8*)((const char*)weff + byw);
                        if (c & 1) ch1 = __builtin_amdgcn_mfma_f32_16x16x32_bf16(af, bfrag[c], ch1, 0, 0, 0);
                        else       ch0 = __builtin_amdgcn_mfma_f32_16x16x32_bf16(af, bfrag[c], ch0, 0, 0, 0);
                    }
                    if (t >= 1) {
                        bf16x8 wyf = *(const bf16x8*)((const char*)wyhs + k * 2);
                        if (c & 1) yc1 = __builtin_amdgcn_mfma_f32_16x16x32_bf16(wyf, bfrag[c], yc1, 0, 0, 0);
                        else       yc0 = __builtin_amdgcn_mfma_f32_16x16x32_bf16(wyf, bfrag[c], yc0, 0, 0, 0);
                    }
                    fired |= (1u << c);
                }
            }
            if (fired != 0xFFu) __builtin_amdgcn_s_sleep(1);
        }

        f32x4 acc  = ch0 + ch1;
        f32x4 accy = yc0 + yc1;
        *(f32x4*)&red[slot][w][0][lane][0] = acc;
        *(f32x4*)&red[slot][w][1][lane][0] = accy;
        __syncthreads();                 // the ONLY barrier per step

        if (t < T_) {
            // D mapping: col = lane&15 (=batch), row = (lane>>4)*4 + reg (=n-local)
            int src = ((nl >> 2) << 4) | b_loc;
            int reg = nl & 3;
            float r = red[slot][0][0][src][reg] + red[slot][1][0][src][reg]
                    + red[slot][2][0][src][reg] + red[slot][3][0][src][reg];
            ahv = 0.9f * ahv + DT * (r + bahv);
            float th = tanhf(ahv);
            float h  = th > 0.f ? th : 0.f;
            unsigned hb = f2bf(h);
            unsigned nb = __shfl_down(hb, 1);
            if ((nl & 1) == 0) {
                unsigned tagw = (unsigned)(((t + 1) >> 1) & 1) << 31;
                unsigned w32 = hb | (nb << 16) | tagw;
                int eidx = ((g * 2 + (slot ^ 1)) * BPG + b_loc) * NREC + n_g;
                __hip_atomic_store((unsigned*)hbuf + (eidx >> 1), w32, __ATOMIC_RELAXED, SCOPE);
            }
            // no ack, no flag: each word self-announces via its tag
        }

        // ---- y for output step t-1 (reduced after the same barrier) ----
        if (t >= 1 && tid < BPG) {
            float yv = red[slot][0][1][tid][0] + red[slot][1][1][tid][0]
                     + red[slot][2][1][tid][0] + red[slot][3][1][tid][0] + byv;
            __builtin_nontemporal_store(yv, &y[((size_t)(g * BPG + tid) * T_ + (t - 1)) * NOUT + m]);
        }
    }
}

extern "C" void kernel_launch(void* const* d_in, const int* in_sizes, int n_in,
                              void* d_out, int out_size, void* d_ws, size_t ws_size,
                              hipStream_t stream) {
    const float* x    = (const float*)d_in[0];
    const float* Wahx = (const float*)d_in[1];
    const float* Wahh = (const float*)d_in[2];
    const float* Wyh  = (const float*)d_in[3];
    const float* bah  = (const float*)d_in[4];
    const float* by   = (const float*)d_in[5];
    const float* ah0  = (const float*)d_in[6];
    const float* mask = (const float*)d_in[7];
    float* y = (float*)d_out;
    char* ws = (char*)d_ws;
    unsigned short* xb   = (unsigned short*)(ws + XB_OFF);
    unsigned short* hbuf = (unsigned short*)(ws + HBUF_OFF);

    (void)in_sizes; (void)n_in; (void)out_size; (void)ws_size;

    // poison hbuf: all tag bits = 1, so phase-0 consumers (t=0,1) cannot
    // false-accept before the first writes land.
    hipMemsetAsync(hbuf, 0xFF, HBUF_BYTES, stream);
    cast_x_kernel<<<dim3(2048), dim3(256), 0, stream>>>(x, xb, (B_ * T_ * NIN) / 4);
    rnn_main<<<dim3(GROUPS * MEMBERS), dim3(256), 0, stream>>>(
        Wahx, Wahh, Wyh, bah, by, ah0, mask, xb, hbuf, y);
}